// Round 12
// baseline (411.667 us; speedup 1.0000x reference)
//
#include <hip/hip_runtime.h>

#define N_NODES 100000
#define N_EDGES 600000
#define NF 128
#define NG 256

typedef _Float16 f16;
typedef f16 half8 __attribute__((ext_vector_type(8)));
typedef f16 half4v __attribute__((ext_vector_type(4)));
typedef float float4v __attribute__((ext_vector_type(4)));

// ---------------- preprocessing: degrees, dinv, CSR ----------------

__global__ void k_count(const int* __restrict__ ei, int* __restrict__ counts) {
    int e = blockIdx.x * 256 + threadIdx.x;
    if (e < N_EDGES) atomicAdd(&counts[ei[N_EDGES + e]], 1);
}

__global__ void k_scan1(const int* __restrict__ counts, int* __restrict__ row_ptr,
                        int* __restrict__ bsums, float* __restrict__ dinv) {
    __shared__ int s[256];
    int b = blockIdx.x, t = threadIdx.x;
    int base = b * 2048 + t * 8;
    int local[8];
    int sum = 0;
#pragma unroll
    for (int q = 0; q < 8; q++) {
        int idx = base + q;
        int v = (idx < N_NODES) ? counts[idx] : 0;
        if (idx < N_NODES) dinv[idx] = 1.0f / sqrtf((float)(v + 1));
        local[q] = sum;
        sum += v;
    }
    s[t] = sum;
    __syncthreads();
    for (int off = 1; off < 256; off <<= 1) {
        int v = 0;
        if (t >= off) v = s[t - off];
        __syncthreads();
        s[t] += v;
        __syncthreads();
    }
    int excl = s[t] - sum;
#pragma unroll
    for (int q = 0; q < 8; q++) {
        int idx = base + q;
        if (idx < N_NODES) row_ptr[idx] = excl + local[q];
    }
    if (t == 255) bsums[b] = s[255];   // raw per-block sums (prefixed in scan3)
}

// scan3 folds the bsums prefix (2048-node group per 8 blocks of 256)
__global__ void k_scan3(int* __restrict__ row_ptr, const int* __restrict__ bsums,
                        int* __restrict__ cursor) {
    __shared__ int pre;
    if (threadIdx.x == 0) {
        int g = blockIdx.x >> 3;
        int s = 0;
        for (int j = 0; j < g; j++) s += bsums[j];
        pre = s;
    }
    __syncthreads();
    int i = blockIdx.x * 256 + threadIdx.x;
    if (i < N_NODES) {
        int v = row_ptr[i] + pre;
        row_ptr[i] = v;
        cursor[i] = v;
        if (i == 0) row_ptr[N_NODES] = N_EDGES;
    }
}

// fill CSR col[]; first 256 blocks also do wprep in FRAGMENT ORDER (R11-proven).
__global__ void k_fill(const int* __restrict__ ei, int* __restrict__ cursor,
                       int* __restrict__ col,
                       const float* __restrict__ W1, const float* __restrict__ W2,
                       const float* __restrict__ W3, const float* __restrict__ W4,
                       f16* __restrict__ wtH, f16* __restrict__ wtL) {
    int e = blockIdx.x * 256 + threadIdx.x;
    if (e < N_EDGES) {
        int d = ei[N_EDGES + e];
        int p = atomicAdd(&cursor[d], 1);
        col[p] = ei[e];
    }
    if (blockIdx.x < 256) {   // wprep: 65536 elements
        int idx = blockIdx.x * 256 + threadIdx.x;
        int layer = idx >> 14;
        int rem = idx & 16383;
        int j = rem & 7;
        int lane = (rem >> 3) & 63;
        int chunk = rem >> 9;          // 0..31 = wave*8 + s*2 + ct
        int wave = chunk >> 3;
        int s = (chunk >> 1) & 3;
        int ct = chunk & 1;
        int n = wave * 32 + ct * 16 + (lane & 15);
        int k = s * 32 + (lane >> 4) * 8 + j;
        const float* W = (layer == 0) ? W1 : (layer == 1) ? W2 : (layer == 2) ? W3 : W4;
        float w = W[k * NF + n];
        f16 h = (f16)w;
        f16 l = (f16)(w - (float)h);
        wtH[layer * 16384 + rem] = h;
        wtL[layer * 16384 + rem] = l;
    }
}

// ---------------- GEMM: Z[M,128] = A[M,128] @ W[128,128], fp16 MFMA --------
// B-frags from fragment-ordered W, DOUBLE-BUFFERED inside the K-loop
// (32 live B VGPRs instead of 64 -> higher occupancy for the staging phase).

template <int XIN>
__global__ __launch_bounds__(256) void k_gemm_mfma(
    const float* __restrict__ X, const f16* __restrict__ A,
    const f16* __restrict__ WTH, const f16* __restrict__ WTL,
    f16* __restrict__ Z, int M) {
    __shared__ __align__(16) f16 As[64 * 136];   // 17408 B; reused for C out

    const int t = threadIdx.x;
    const int row0 = blockIdx.x * 64;
    const int wave = t >> 6;
    const int lane = t & 63;
    const int nl = lane & 15;
    const int quad = lane >> 4;

    auto bofs = [&](int s, int ct) {
        return (size_t)((((wave * 8 + s * 2 + ct) * 64) + lane) << 3);
    };

    // s=0 B fragments (prefetch before barrier)
    half8 cbh[2], cbl[2];
    cbh[0] = *(const half8*)(WTH + bofs(0, 0));
    cbh[1] = *(const half8*)(WTH + bofs(0, 1));
    cbl[0] = *(const half8*)(WTL + bofs(0, 0));
    cbl[1] = *(const half8*)(WTL + bofs(0, 1));

    if (XIN) {
#pragma unroll
        for (int q = 0; q < 8; q++) {
            int lin = t + q * 256;
            int r = lin >> 5, c4 = lin & 31;
            float4 v = make_float4(0.f, 0.f, 0.f, 0.f);
            if (row0 + r < M) v = ((const float4*)(X + (size_t)(row0 + r) * NF))[c4];
            half4v hv = {(f16)v.x, (f16)v.y, (f16)v.z, (f16)v.w};
            *(half4v*)&As[r * 136 + c4 * 4] = hv;
        }
    } else {
#pragma unroll
        for (int q = 0; q < 4; q++) {
            int lin = t + q * 256;
            int r = lin >> 4, c8 = lin & 15;
            half8 v = {};
            if (row0 + r < M) v = *(const half8*)(A + (size_t)(row0 + r) * NF + c8 * 8);
            *(half8*)&As[r * 136 + c8 * 8] = v;
        }
    }
    __syncthreads();

    float4v acc[2][4];
#pragma unroll
    for (int ct = 0; ct < 2; ct++)
#pragma unroll
        for (int rt = 0; rt < 4; rt++) acc[ct][rt] = (float4v)0.f;

#pragma unroll
    for (int s = 0; s < 4; s++) {
        half8 nbh[2], nbl[2];
        if (s < 3) {   // prefetch next K-step's B while MFMA'ing this one
            nbh[0] = *(const half8*)(WTH + bofs(s + 1, 0));
            nbh[1] = *(const half8*)(WTH + bofs(s + 1, 1));
            nbl[0] = *(const half8*)(WTL + bofs(s + 1, 0));
            nbl[1] = *(const half8*)(WTL + bofs(s + 1, 1));
        }
        half8 fa[4];
#pragma unroll
        for (int rt = 0; rt < 4; rt++)
            fa[rt] = *(half8*)&As[(rt * 16 + nl) * 136 + s * 32 + quad * 8];
#pragma unroll
        for (int ct = 0; ct < 2; ct++)
#pragma unroll
            for (int rt = 0; rt < 4; rt++) {
                acc[ct][rt] = __builtin_amdgcn_mfma_f32_16x16x32_f16(fa[rt], cbh[ct], acc[ct][rt], 0, 0, 0);
                acc[ct][rt] = __builtin_amdgcn_mfma_f32_16x16x32_f16(fa[rt], cbl[ct], acc[ct][rt], 0, 0, 0);
            }
        if (s < 3) {
            cbh[0] = nbh[0]; cbh[1] = nbh[1];
            cbl[0] = nbl[0]; cbl[1] = nbl[1];
        }
    }

    __syncthreads();
#pragma unroll
    for (int ct = 0; ct < 2; ct++)
#pragma unroll
        for (int rt = 0; rt < 4; rt++)
#pragma unroll
            for (int r = 0; r < 4; r++)
                As[(rt * 16 + quad * 4 + r) * 136 + wave * 32 + ct * 16 + nl] =
                    (f16)acc[ct][rt][r];
    __syncthreads();
#pragma unroll
    for (int q = 0; q < 4; q++) {
        int lin = t + q * 256;
        int r = lin >> 4, c8 = lin & 15;
        if (row0 + r < M)
            *(half8*)(Z + (size_t)(row0 + r) * NF + c8 * 8) = *(half8*)&As[r * 136 + c8 * 8];
    }
}

// ---------------- aggregation (R7/R11-proven, frozen) ----------------------

#define ACHUNK 4

__global__ __launch_bounds__(256) void k_agg(const f16* __restrict__ z,
                                             const float* __restrict__ dinv,
                                             const int* __restrict__ row_ptr,
                                             const int* __restrict__ col,
                                             const float* __restrict__ bias,
                                             f16* __restrict__ h) {
    const int t = threadIdx.x;
    const int slot = t >> 4;            // 0..15 in block
    const int fl = t & 15;              // half8 chunk within row
    const int sbase = (t & 48);         // slot base lane within wave
    const int n0 = (blockIdx.x * 16 + slot) * ACHUNK;
    const half8* z8 = (const half8*)z;

    float bb[8];
    {
        float4 b0 = ((const float4*)bias)[fl * 2];
        float4 b1 = ((const float4*)bias)[fl * 2 + 1];
        bb[0] = b0.x; bb[1] = b0.y; bb[2] = b0.z; bb[3] = b0.w;
        bb[4] = b1.x; bb[5] = b1.y; bb[6] = b1.z; bb[7] = b1.w;
    }

    for (int n = n0; n < n0 + ACHUNK && n < N_NODES; n++) {
        const float di = dinv[n];
        const int beg = row_ptr[n];
        const int end = row_ptr[n + 1];

        float acc[8];
        {   // self-loop + bias
            half8 v = z8[(size_t)n * 16 + fl];
            float w = di * di;
#pragma unroll
            for (int j = 0; j < 8; j++) acc[j] = bb[j] + (float)v[j] * w;
        }

        for (int c = beg; c < end; c += 16) {
            int mcnt = end - c; if (mcnt > 16) mcnt = 16;
            int ce = c + fl;
            int colv = (ce < end) ? col[ce] : 0;
            float dvv = dinv[colv];

            int j = 0;
            for (; j + 1 < mcnt; j += 2) {
                int s1 = __shfl(colv, sbase + j, 64);
                float w1 = __shfl(dvv, sbase + j, 64) * di;
                int s2 = __shfl(colv, sbase + j + 1, 64);
                float w2 = __shfl(dvv, sbase + j + 1, 64) * di;
                half8 v1 = z8[(size_t)s1 * 16 + fl];
                half8 v2 = z8[(size_t)s2 * 16 + fl];
#pragma unroll
                for (int q = 0; q < 8; q++) acc[q] += (float)v1[q] * w1;
#pragma unroll
                for (int q = 0; q < 8; q++) acc[q] += (float)v2[q] * w2;
            }
            if (j < mcnt) {
                int s1 = __shfl(colv, sbase + j, 64);
                float w1 = __shfl(dvv, sbase + j, 64) * di;
                half8 v1 = z8[(size_t)s1 * 16 + fl];
#pragma unroll
                for (int q = 0; q < 8; q++) acc[q] += (float)v1[q] * w1;
            }
        }

        half8 o;
#pragma unroll
        for (int j = 0; j < 8; j++) o[j] = (f16)fmaxf(acc[j], 0.f);
        ((half8*)h)[(size_t)n * 16 + fl] = o;
    }
}

// ---------------- mean pool, vectorized (16-lane slots x half8) ------------
// slot covers PCHUNK consecutive nodes; register fp32 partials, atomic flush
// only at graph boundaries (~800k total atomics, well below R8's 6.4M).

#define PCHUNK 16

__global__ __launch_bounds__(256) void k_pool3(const f16* __restrict__ h,
                                               const int* __restrict__ batch,
                                               float* __restrict__ pooled) {
    int t = threadIdx.x;
    int slot = t >> 4, fl = t & 15;
    int n0 = (blockIdx.x * 16 + slot) * PCHUNK;
    if (n0 >= N_NODES) return;
    int n1 = n0 + PCHUNK; if (n1 > N_NODES) n1 = N_NODES;
    const half8* h8 = (const half8*)h;

    int g = batch[n0];
    float ps[8];
#pragma unroll
    for (int j = 0; j < 8; j++) ps[j] = 0.f;

    for (int n = n0; n < n1; n++) {
        int gn = batch[n];
        if (gn != g) {
#pragma unroll
            for (int j = 0; j < 8; j++)
                atomicAdd(&pooled[g * NF + fl * 8 + j], ps[j]);
            g = gn;
#pragma unroll
            for (int j = 0; j < 8; j++) ps[j] = 0.f;
        }
        half8 v = h8[(size_t)n * 16 + fl];
#pragma unroll
        for (int j = 0; j < 8; j++) ps[j] += (float)v[j];
    }
#pragma unroll
    for (int j = 0; j < 8; j++)
        atomicAdd(&pooled[g * NF + fl * 8 + j], ps[j]);
}

// ---------------- summary MLP ----------------

__global__ void k_mlp(const float* __restrict__ pooled, const int* __restrict__ batch,
                      const float* __restrict__ Ws1, const float* __restrict__ bs1,
                      const float* __restrict__ Ws2, const float* __restrict__ bs2,
                      float* __restrict__ out) {
    __shared__ float row[NF];
    __shared__ float red[NF];
    int g = blockIdx.x, f = threadIdx.x;
    int lo = 0, hi = N_NODES;
    while (lo < hi) { int mid = (lo + hi) >> 1; if (batch[mid] < g) lo = mid + 1; else hi = mid; }
    int start = lo;
    hi = N_NODES;
    while (lo < hi) { int mid = (lo + hi) >> 1; if (batch[mid] < g + 1) lo = mid + 1; else hi = mid; }
    float cnt = (float)(lo - start);
    row[f] = pooled[g * NF + f] / fmaxf(cnt, 1.f);
    __syncthreads();
    float t = bs1[f];
    for (int k = 0; k < NF; k++) t += row[k] * Ws1[k * NF + f];
    t = fmaxf(t, 0.f);
    red[f] = t * Ws2[f];
    __syncthreads();
    for (int s = 64; s > 0; s >>= 1) {
        if (f < s) red[f] += red[f + s];
        __syncthreads();
    }
    if (f == 0) out[g] = red[0] + bs2[0];
}

// ---------------- driver ----------------

extern "C" void kernel_launch(void* const* d_in, const int* in_sizes, int n_in,
                              void* d_out, int out_size, void* d_ws, size_t ws_size,
                              hipStream_t stream) {
    const float* x    = (const float*)d_in[0];
    const int*   ei   = (const int*)d_in[1];
    const int*   batch= (const int*)d_in[2];
    const float* W1 = (const float*)d_in[3];  const float* b1 = (const float*)d_in[4];
    const float* W2 = (const float*)d_in[5];  const float* b2 = (const float*)d_in[6];
    const float* W3 = (const float*)d_in[7];  const float* b3 = (const float*)d_in[8];
    const float* W4 = (const float*)d_in[9];  const float* b4 = (const float*)d_in[10];
    const float* Ws1= (const float*)d_in[11]; const float* bs1= (const float*)d_in[12];
    const float* Ws2= (const float*)d_in[13]; const float* bs2= (const float*)d_in[14];
    float* out = (float*)d_out;

    char* ws = (char*)d_ws;
    size_t off = 0;
    auto alloc = [&](size_t bytes) {
        void* p = ws + off;
        off += (bytes + 255) & ~(size_t)255;
        return p;
    };
    f16*   bufZ   = (f16*)alloc((size_t)N_NODES * NF * 2);
    f16*   bufH   = (f16*)alloc((size_t)N_NODES * NF * 2);
    f16*   wtH    = (f16*)alloc((size_t)4 * NF * NF * 2);
    f16*   wtL    = (f16*)alloc((size_t)4 * NF * NF * 2);
    int*   counts = (int*)alloc((size_t)N_NODES * 4);
    int*   row_ptr= (int*)alloc((size_t)(N_NODES + 1) * 4);
    int*   cursor = (int*)alloc((size_t)N_NODES * 4);
    int*   col    = (int*)alloc((size_t)N_EDGES * 4);
    int*   bsums  = (int*)alloc(64 * 4);
    float* dinv   = (float*)alloc((size_t)N_NODES * 4);
    float* pooled = (float*)alloc((size_t)NG * NF * 4);

    hipMemsetAsync(counts, 0, (size_t)N_NODES * 4, stream);
    hipMemsetAsync(pooled, 0, (size_t)NG * NF * 4, stream);
    k_count<<<(N_EDGES + 255) / 256, 256, 0, stream>>>(ei, counts);
    int nscan = (N_NODES + 2047) / 2048;  // 49
    k_scan1<<<nscan, 256, 0, stream>>>(counts, row_ptr, bsums, dinv);
    k_scan3<<<(N_NODES + 255) / 256, 256, 0, stream>>>(row_ptr, bsums, cursor);
    k_fill<<<(N_EDGES + 255) / 256, 256, 0, stream>>>(ei, cursor, col,
                                                      W1, W2, W3, W4, wtH, wtL);

    int gblocks = (N_NODES + 63) / 64;                          // 1563
    int ablocks = (N_NODES + 16 * ACHUNK - 1) / (16 * ACHUNK);  // 1563
    k_gemm_mfma<1><<<gblocks, 256, 0, stream>>>(x, nullptr, wtH, wtL, bufZ, N_NODES);
    k_agg<<<ablocks, 256, 0, stream>>>(bufZ, dinv, row_ptr, col, b1, bufH);
    k_gemm_mfma<0><<<gblocks, 256, 0, stream>>>(nullptr, bufH, wtH + 16384, wtL + 16384, bufZ, N_NODES);
    k_agg<<<ablocks, 256, 0, stream>>>(bufZ, dinv, row_ptr, col, b2, bufH);
    k_gemm_mfma<0><<<gblocks, 256, 0, stream>>>(nullptr, bufH, wtH + 32768, wtL + 32768, bufZ, N_NODES);
    k_agg<<<ablocks, 256, 0, stream>>>(bufZ, dinv, row_ptr, col, b3, bufH);
    k_gemm_mfma<0><<<gblocks, 256, 0, stream>>>(nullptr, bufH, wtH + 49152, wtL + 49152, bufZ, N_NODES);
    k_agg<<<ablocks, 256, 0, stream>>>(bufZ, dinv, row_ptr, col, b4, bufH);

    int pblocks = (N_NODES + 16 * PCHUNK - 1) / (16 * PCHUNK);  // 391
    k_pool3<<<pblocks, 256, 0, stream>>>(bufH, batch, pooled);
    k_mlp<<<NG, 128, 0, stream>>>(pooled, batch, Ws1, bs1, Ws2, bs2, out);
}

// Round 13
// 386.642 us; speedup vs baseline: 1.0647x; 1.0647x over previous
//
#include <hip/hip_runtime.h>

#define N_NODES 100000
#define N_EDGES 600000
#define NF 128
#define NG 256

typedef _Float16 f16;
typedef f16 half8 __attribute__((ext_vector_type(8)));
typedef f16 half4v __attribute__((ext_vector_type(4)));
typedef float float4v __attribute__((ext_vector_type(4)));

// ---------------- preprocessing: degrees, dinv, CSR ----------------

__global__ void k_count(const int* __restrict__ ei, int* __restrict__ counts) {
    int e = blockIdx.x * 256 + threadIdx.x;
    if (e < N_EDGES) atomicAdd(&counts[ei[N_EDGES + e]], 1);
}

__global__ void k_scan1(const int* __restrict__ counts, int* __restrict__ row_ptr,
                        int* __restrict__ bsums, float* __restrict__ dinv) {
    __shared__ int s[256];
    int b = blockIdx.x, t = threadIdx.x;
    int base = b * 2048 + t * 8;
    int local[8];
    int sum = 0;
#pragma unroll
    for (int q = 0; q < 8; q++) {
        int idx = base + q;
        int v = (idx < N_NODES) ? counts[idx] : 0;
        if (idx < N_NODES) dinv[idx] = 1.0f / sqrtf((float)(v + 1));
        local[q] = sum;
        sum += v;
    }
    s[t] = sum;
    __syncthreads();
    for (int off = 1; off < 256; off <<= 1) {
        int v = 0;
        if (t >= off) v = s[t - off];
        __syncthreads();
        s[t] += v;
        __syncthreads();
    }
    int excl = s[t] - sum;
#pragma unroll
    for (int q = 0; q < 8; q++) {
        int idx = base + q;
        if (idx < N_NODES) row_ptr[idx] = excl + local[q];
    }
    if (t == 255) bsums[b] = s[255];   // raw per-block sums (prefixed in scan3)
}

// scan3 folds the bsums prefix (2048-node group per 8 blocks of 256)
__global__ void k_scan3(int* __restrict__ row_ptr, const int* __restrict__ bsums,
                        int* __restrict__ cursor) {
    __shared__ int pre;
    if (threadIdx.x == 0) {
        int g = blockIdx.x >> 3;
        int s = 0;
        for (int j = 0; j < g; j++) s += bsums[j];
        pre = s;
    }
    __syncthreads();
    int i = blockIdx.x * 256 + threadIdx.x;
    if (i < N_NODES) {
        int v = row_ptr[i] + pre;
        row_ptr[i] = v;
        cursor[i] = v;
        if (i == 0) row_ptr[N_NODES] = N_EDGES;
    }
}

// fill CSR col[]; first 256 blocks also do wprep in FRAGMENT ORDER (R11-proven).
__global__ void k_fill(const int* __restrict__ ei, int* __restrict__ cursor,
                       int* __restrict__ col,
                       const float* __restrict__ W1, const float* __restrict__ W2,
                       const float* __restrict__ W3, const float* __restrict__ W4,
                       f16* __restrict__ wtH, f16* __restrict__ wtL) {
    int e = blockIdx.x * 256 + threadIdx.x;
    if (e < N_EDGES) {
        int d = ei[N_EDGES + e];
        int p = atomicAdd(&cursor[d], 1);
        col[p] = ei[e];
    }
    if (blockIdx.x < 256) {   // wprep: 65536 elements
        int idx = blockIdx.x * 256 + threadIdx.x;
        int layer = idx >> 14;
        int rem = idx & 16383;
        int j = rem & 7;
        int lane = (rem >> 3) & 63;
        int chunk = rem >> 9;          // 0..31 = wave*8 + s*2 + ct
        int wave = chunk >> 3;
        int s = (chunk >> 1) & 3;
        int ct = chunk & 1;
        int n = wave * 32 + ct * 16 + (lane & 15);
        int k = s * 32 + (lane >> 4) * 8 + j;
        const float* W = (layer == 0) ? W1 : (layer == 1) ? W2 : (layer == 2) ? W3 : W4;
        float w = W[k * NF + n];
        f16 h = (f16)w;
        f16 l = (f16)(w - (float)h);
        wtH[layer * 16384 + rem] = h;
        wtL[layer * 16384 + rem] = l;
    }
}

// ---------------- GEMM: Z[M,128] = A[M,128] @ W[128,128], fp16 MFMA --------
// Fragment-ordered W (R11 win) + K-loop double-buffered B (R12 win).

template <int XIN>
__global__ __launch_bounds__(256) void k_gemm_mfma(
    const float* __restrict__ X, const f16* __restrict__ A,
    const f16* __restrict__ WTH, const f16* __restrict__ WTL,
    f16* __restrict__ Z, int M) {
    __shared__ __align__(16) f16 As[64 * 136];   // 17408 B; reused for C out

    const int t = threadIdx.x;
    const int row0 = blockIdx.x * 64;
    const int wave = t >> 6;
    const int lane = t & 63;
    const int nl = lane & 15;
    const int quad = lane >> 4;

    auto bofs = [&](int s, int ct) {
        return (size_t)((((wave * 8 + s * 2 + ct) * 64) + lane) << 3);
    };

    // s=0 B fragments (prefetch before barrier)
    half8 cbh[2], cbl[2];
    cbh[0] = *(const half8*)(WTH + bofs(0, 0));
    cbh[1] = *(const half8*)(WTH + bofs(0, 1));
    cbl[0] = *(const half8*)(WTL + bofs(0, 0));
    cbl[1] = *(const half8*)(WTL + bofs(0, 1));

    if (XIN) {
#pragma unroll
        for (int q = 0; q < 8; q++) {
            int lin = t + q * 256;
            int r = lin >> 5, c4 = lin & 31;
            float4 v = make_float4(0.f, 0.f, 0.f, 0.f);
            if (row0 + r < M) v = ((const float4*)(X + (size_t)(row0 + r) * NF))[c4];
            half4v hv = {(f16)v.x, (f16)v.y, (f16)v.z, (f16)v.w};
            *(half4v*)&As[r * 136 + c4 * 4] = hv;
        }
    } else {
#pragma unroll
        for (int q = 0; q < 4; q++) {
            int lin = t + q * 256;
            int r = lin >> 4, c8 = lin & 15;
            half8 v = {};
            if (row0 + r < M) v = *(const half8*)(A + (size_t)(row0 + r) * NF + c8 * 8);
            *(half8*)&As[r * 136 + c8 * 8] = v;
        }
    }
    __syncthreads();

    float4v acc[2][4];
#pragma unroll
    for (int ct = 0; ct < 2; ct++)
#pragma unroll
        for (int rt = 0; rt < 4; rt++) acc[ct][rt] = (float4v)0.f;

#pragma unroll
    for (int s = 0; s < 4; s++) {
        half8 nbh[2], nbl[2];
        if (s < 3) {   // prefetch next K-step's B while MFMA'ing this one
            nbh[0] = *(const half8*)(WTH + bofs(s + 1, 0));
            nbh[1] = *(const half8*)(WTH + bofs(s + 1, 1));
            nbl[0] = *(const half8*)(WTL + bofs(s + 1, 0));
            nbl[1] = *(const half8*)(WTL + bofs(s + 1, 1));
        }
        half8 fa[4];
#pragma unroll
        for (int rt = 0; rt < 4; rt++)
            fa[rt] = *(half8*)&As[(rt * 16 + nl) * 136 + s * 32 + quad * 8];
#pragma unroll
        for (int ct = 0; ct < 2; ct++)
#pragma unroll
            for (int rt = 0; rt < 4; rt++) {
                acc[ct][rt] = __builtin_amdgcn_mfma_f32_16x16x32_f16(fa[rt], cbh[ct], acc[ct][rt], 0, 0, 0);
                acc[ct][rt] = __builtin_amdgcn_mfma_f32_16x16x32_f16(fa[rt], cbl[ct], acc[ct][rt], 0, 0, 0);
            }
        if (s < 3) {
            cbh[0] = nbh[0]; cbh[1] = nbh[1];
            cbl[0] = nbl[0]; cbl[1] = nbl[1];
        }
    }

    __syncthreads();
#pragma unroll
    for (int ct = 0; ct < 2; ct++)
#pragma unroll
        for (int rt = 0; rt < 4; rt++)
#pragma unroll
            for (int r = 0; r < 4; r++)
                As[(rt * 16 + quad * 4 + r) * 136 + wave * 32 + ct * 16 + nl] =
                    (f16)acc[ct][rt][r];
    __syncthreads();
#pragma unroll
    for (int q = 0; q < 4; q++) {
        int lin = t + q * 256;
        int r = lin >> 4, c8 = lin & 15;
        if (row0 + r < M)
            *(half8*)(Z + (size_t)(row0 + r) * NF + c8 * 8) = *(half8*)&As[r * 136 + c8 * 8];
    }
}

// ---------------- aggregation (R7/R11-proven, frozen) ----------------------

#define ACHUNK 4

__global__ __launch_bounds__(256) void k_agg(const f16* __restrict__ z,
                                             const float* __restrict__ dinv,
                                             const int* __restrict__ row_ptr,
                                             const int* __restrict__ col,
                                             const float* __restrict__ bias,
                                             f16* __restrict__ h) {
    const int t = threadIdx.x;
    const int slot = t >> 4;            // 0..15 in block
    const int fl = t & 15;              // half8 chunk within row
    const int sbase = (t & 48);         // slot base lane within wave
    const int n0 = (blockIdx.x * 16 + slot) * ACHUNK;
    const half8* z8 = (const half8*)z;

    float bb[8];
    {
        float4 b0 = ((const float4*)bias)[fl * 2];
        float4 b1 = ((const float4*)bias)[fl * 2 + 1];
        bb[0] = b0.x; bb[1] = b0.y; bb[2] = b0.z; bb[3] = b0.w;
        bb[4] = b1.x; bb[5] = b1.y; bb[6] = b1.z; bb[7] = b1.w;
    }

    for (int n = n0; n < n0 + ACHUNK && n < N_NODES; n++) {
        const float di = dinv[n];
        const int beg = row_ptr[n];
        const int end = row_ptr[n + 1];

        float acc[8];
        {   // self-loop + bias
            half8 v = z8[(size_t)n * 16 + fl];
            float w = di * di;
#pragma unroll
            for (int j = 0; j < 8; j++) acc[j] = bb[j] + (float)v[j] * w;
        }

        for (int c = beg; c < end; c += 16) {
            int mcnt = end - c; if (mcnt > 16) mcnt = 16;
            int ce = c + fl;
            int colv = (ce < end) ? col[ce] : 0;
            float dvv = dinv[colv];

            int j = 0;
            for (; j + 1 < mcnt; j += 2) {
                int s1 = __shfl(colv, sbase + j, 64);
                float w1 = __shfl(dvv, sbase + j, 64) * di;
                int s2 = __shfl(colv, sbase + j + 1, 64);
                float w2 = __shfl(dvv, sbase + j + 1, 64) * di;
                half8 v1 = z8[(size_t)s1 * 16 + fl];
                half8 v2 = z8[(size_t)s2 * 16 + fl];
#pragma unroll
                for (int q = 0; q < 8; q++) acc[q] += (float)v1[q] * w1;
#pragma unroll
                for (int q = 0; q < 8; q++) acc[q] += (float)v2[q] * w2;
            }
            if (j < mcnt) {
                int s1 = __shfl(colv, sbase + j, 64);
                float w1 = __shfl(dvv, sbase + j, 64) * di;
                half8 v1 = z8[(size_t)s1 * 16 + fl];
#pragma unroll
                for (int q = 0; q < 8; q++) acc[q] += (float)v1[q] * w1;
            }
        }

        half8 o;
#pragma unroll
        for (int j = 0; j < 8; j++) o[j] = (f16)fmaxf(acc[j], 0.f);
        ((half8*)h)[(size_t)n * 16 + fl] = o;
    }
}

// ---------------- node-parallel mean pool (R11-proven pool2) ----------------
// 128 threads = full row; 100k threads total; per-node scalar loads but
// massive TLP. R12's slot-vectorized pool3 (6256 slots) regressed 10->45 us.

#define POOL_CHUNK 64

__global__ __launch_bounds__(128) void k_pool2(const f16* __restrict__ h,
                                               const int* __restrict__ batch,
                                               float* __restrict__ pooled) {
    int f = threadIdx.x;
    int n0 = blockIdx.x * POOL_CHUNK;
    int n1 = n0 + POOL_CHUNK;
    if (n1 > N_NODES) n1 = N_NODES;
    if (n0 >= N_NODES) return;
    int g = batch[n0];
    float acc = 0.f;
    for (int n = n0; n < n1; n++) {
        int gn = batch[n];
        if (gn != g) {
            atomicAdd(&pooled[g * NF + f], acc);
            acc = 0.f;
            g = gn;
        }
        acc += (float)h[(size_t)n * NF + f];   // h already relu'd
    }
    atomicAdd(&pooled[g * NF + f], acc);
}

// ---------------- summary MLP ----------------

__global__ void k_mlp(const float* __restrict__ pooled, const int* __restrict__ batch,
                      const float* __restrict__ Ws1, const float* __restrict__ bs1,
                      const float* __restrict__ Ws2, const float* __restrict__ bs2,
                      float* __restrict__ out) {
    __shared__ float row[NF];
    __shared__ float red[NF];
    int g = blockIdx.x, f = threadIdx.x;
    int lo = 0, hi = N_NODES;
    while (lo < hi) { int mid = (lo + hi) >> 1; if (batch[mid] < g) lo = mid + 1; else hi = mid; }
    int start = lo;
    hi = N_NODES;
    while (lo < hi) { int mid = (lo + hi) >> 1; if (batch[mid] < g + 1) lo = mid + 1; else hi = mid; }
    float cnt = (float)(lo - start);
    row[f] = pooled[g * NF + f] / fmaxf(cnt, 1.f);
    __syncthreads();
    float t = bs1[f];
    for (int k = 0; k < NF; k++) t += row[k] * Ws1[k * NF + f];
    t = fmaxf(t, 0.f);
    red[f] = t * Ws2[f];
    __syncthreads();
    for (int s = 64; s > 0; s >>= 1) {
        if (f < s) red[f] += red[f + s];
        __syncthreads();
    }
    if (f == 0) out[g] = red[0] + bs2[0];
}

// ---------------- driver ----------------

extern "C" void kernel_launch(void* const* d_in, const int* in_sizes, int n_in,
                              void* d_out, int out_size, void* d_ws, size_t ws_size,
                              hipStream_t stream) {
    const float* x    = (const float*)d_in[0];
    const int*   ei   = (const int*)d_in[1];
    const int*   batch= (const int*)d_in[2];
    const float* W1 = (const float*)d_in[3];  const float* b1 = (const float*)d_in[4];
    const float* W2 = (const float*)d_in[5];  const float* b2 = (const float*)d_in[6];
    const float* W3 = (const float*)d_in[7];  const float* b3 = (const float*)d_in[8];
    const float* W4 = (const float*)d_in[9];  const float* b4 = (const float*)d_in[10];
    const float* Ws1= (const float*)d_in[11]; const float* bs1= (const float*)d_in[12];
    const float* Ws2= (const float*)d_in[13]; const float* bs2= (const float*)d_in[14];
    float* out = (float*)d_out;

    char* ws = (char*)d_ws;
    size_t off = 0;
    auto alloc = [&](size_t bytes) {
        void* p = ws + off;
        off += (bytes + 255) & ~(size_t)255;
        return p;
    };
    f16*   bufZ   = (f16*)alloc((size_t)N_NODES * NF * 2);
    f16*   bufH   = (f16*)alloc((size_t)N_NODES * NF * 2);
    f16*   wtH    = (f16*)alloc((size_t)4 * NF * NF * 2);
    f16*   wtL    = (f16*)alloc((size_t)4 * NF * NF * 2);
    int*   counts = (int*)alloc((size_t)N_NODES * 4);
    int*   row_ptr= (int*)alloc((size_t)(N_NODES + 1) * 4);
    int*   cursor = (int*)alloc((size_t)N_NODES * 4);
    int*   col    = (int*)alloc((size_t)N_EDGES * 4);
    int*   bsums  = (int*)alloc(64 * 4);
    float* dinv   = (float*)alloc((size_t)N_NODES * 4);
    float* pooled = (float*)alloc((size_t)NG * NF * 4);

    hipMemsetAsync(counts, 0, (size_t)N_NODES * 4, stream);
    hipMemsetAsync(pooled, 0, (size_t)NG * NF * 4, stream);
    k_count<<<(N_EDGES + 255) / 256, 256, 0, stream>>>(ei, counts);
    int nscan = (N_NODES + 2047) / 2048;  // 49
    k_scan1<<<nscan, 256, 0, stream>>>(counts, row_ptr, bsums, dinv);
    k_scan3<<<(N_NODES + 255) / 256, 256, 0, stream>>>(row_ptr, bsums, cursor);
    k_fill<<<(N_EDGES + 255) / 256, 256, 0, stream>>>(ei, cursor, col,
                                                      W1, W2, W3, W4, wtH, wtL);

    int gblocks = (N_NODES + 63) / 64;                          // 1563
    int ablocks = (N_NODES + 16 * ACHUNK - 1) / (16 * ACHUNK);  // 1563
    k_gemm_mfma<1><<<gblocks, 256, 0, stream>>>(x, nullptr, wtH, wtL, bufZ, N_NODES);
    k_agg<<<ablocks, 256, 0, stream>>>(bufZ, dinv, row_ptr, col, b1, bufH);
    k_gemm_mfma<0><<<gblocks, 256, 0, stream>>>(nullptr, bufH, wtH + 16384, wtL + 16384, bufZ, N_NODES);
    k_agg<<<ablocks, 256, 0, stream>>>(bufZ, dinv, row_ptr, col, b2, bufH);
    k_gemm_mfma<0><<<gblocks, 256, 0, stream>>>(nullptr, bufH, wtH + 32768, wtL + 32768, bufZ, N_NODES);
    k_agg<<<ablocks, 256, 0, stream>>>(bufZ, dinv, row_ptr, col, b3, bufH);
    k_gemm_mfma<0><<<gblocks, 256, 0, stream>>>(nullptr, bufH, wtH + 49152, wtL + 49152, bufZ, N_NODES);
    k_agg<<<ablocks, 256, 0, stream>>>(bufZ, dinv, row_ptr, col, b4, bufH);

    int pblocks = (N_NODES + POOL_CHUNK - 1) / POOL_CHUNK;      // 1563
    k_pool2<<<pblocks, 128, 0, stream>>>(bufH, batch, pooled);
    k_mlp<<<NG, 128, 0, stream>>>(pooled, batch, Ws1, bs1, Ws2, bs2, out);
}

// Round 14
// 381.624 us; speedup vs baseline: 1.0787x; 1.0131x over previous
//
#include <hip/hip_runtime.h>

#define N_NODES 100000
#define N_EDGES 600000
#define NF 128
#define NG 256

typedef _Float16 f16;
typedef f16 half8 __attribute__((ext_vector_type(8)));
typedef f16 half4v __attribute__((ext_vector_type(4)));
typedef float float4v __attribute__((ext_vector_type(4)));

// ---------------- preprocessing: degrees, dinv, CSR ----------------

__global__ void k_count(const int* __restrict__ ei, int* __restrict__ counts) {
    int e = blockIdx.x * 256 + threadIdx.x;
    if (e < N_EDGES) atomicAdd(&counts[ei[N_EDGES + e]], 1);
}

__global__ void k_scan1(const int* __restrict__ counts, int* __restrict__ row_ptr,
                        int* __restrict__ bsums, float* __restrict__ dinv) {
    __shared__ int s[256];
    int b = blockIdx.x, t = threadIdx.x;
    int base = b * 2048 + t * 8;
    int local[8];
    int sum = 0;
#pragma unroll
    for (int q = 0; q < 8; q++) {
        int idx = base + q;
        int v = (idx < N_NODES) ? counts[idx] : 0;
        if (idx < N_NODES) dinv[idx] = 1.0f / sqrtf((float)(v + 1));
        local[q] = sum;
        sum += v;
    }
    s[t] = sum;
    __syncthreads();
    for (int off = 1; off < 256; off <<= 1) {
        int v = 0;
        if (t >= off) v = s[t - off];
        __syncthreads();
        s[t] += v;
        __syncthreads();
    }
    int excl = s[t] - sum;
#pragma unroll
    for (int q = 0; q < 8; q++) {
        int idx = base + q;
        if (idx < N_NODES) row_ptr[idx] = excl + local[q];
    }
    if (t == 255) bsums[b] = s[255];   // raw per-block sums (prefixed in scan3)
}

// scan3 folds the bsums prefix (2048-node group per 8 blocks of 256)
__global__ void k_scan3(int* __restrict__ row_ptr, const int* __restrict__ bsums,
                        int* __restrict__ cursor) {
    __shared__ int pre;
    if (threadIdx.x == 0) {
        int g = blockIdx.x >> 3;
        int s = 0;
        for (int j = 0; j < g; j++) s += bsums[j];
        pre = s;
    }
    __syncthreads();
    int i = blockIdx.x * 256 + threadIdx.x;
    if (i < N_NODES) {
        int v = row_ptr[i] + pre;
        row_ptr[i] = v;
        cursor[i] = v;
        if (i == 0) row_ptr[N_NODES] = N_EDGES;
    }
}

// fill CSR col[]; first 256 blocks also do wprep in FRAGMENT ORDER (R11-proven).
// R14: single fp16 W (no lo-plane) — spends accuracy headroom (7.6e-6 of 2.64e-5)
// to halve gemm MFMA count and B traffic.
__global__ void k_fill(const int* __restrict__ ei, int* __restrict__ cursor,
                       int* __restrict__ col,
                       const float* __restrict__ W1, const float* __restrict__ W2,
                       const float* __restrict__ W3, const float* __restrict__ W4,
                       f16* __restrict__ wtH) {
    int e = blockIdx.x * 256 + threadIdx.x;
    if (e < N_EDGES) {
        int d = ei[N_EDGES + e];
        int p = atomicAdd(&cursor[d], 1);
        col[p] = ei[e];
    }
    if (blockIdx.x < 256) {   // wprep: 65536 elements
        int idx = blockIdx.x * 256 + threadIdx.x;
        int layer = idx >> 14;
        int rem = idx & 16383;
        int j = rem & 7;
        int lane = (rem >> 3) & 63;
        int chunk = rem >> 9;          // 0..31 = wave*8 + s*2 + ct
        int wave = chunk >> 3;
        int s = (chunk >> 1) & 3;
        int ct = chunk & 1;
        int n = wave * 32 + ct * 16 + (lane & 15);
        int k = s * 32 + (lane >> 4) * 8 + j;
        const float* W = (layer == 0) ? W1 : (layer == 1) ? W2 : (layer == 2) ? W3 : W4;
        wtH[layer * 16384 + rem] = (f16)W[k * NF + n];
    }
}

// ---------------- GEMM: Z[M,128] = A[M,128] @ W[128,128], fp16 MFMA --------
// Fragment-ordered W (R11 win) + K-loop double-buffered B (R12 win);
// single fp16 W plane (R14): 8 MFMAs per K-step.

template <int XIN>
__global__ __launch_bounds__(256) void k_gemm_mfma(
    const float* __restrict__ X, const f16* __restrict__ A,
    const f16* __restrict__ WTH,
    f16* __restrict__ Z, int M) {
    __shared__ __align__(16) f16 As[64 * 136];   // 17408 B; reused for C out

    const int t = threadIdx.x;
    const int row0 = blockIdx.x * 64;
    const int wave = t >> 6;
    const int lane = t & 63;
    const int nl = lane & 15;
    const int quad = lane >> 4;

    auto bofs = [&](int s, int ct) {
        return (size_t)((((wave * 8 + s * 2 + ct) * 64) + lane) << 3);
    };

    // s=0 B fragments (prefetch before barrier)
    half8 cbh[2];
    cbh[0] = *(const half8*)(WTH + bofs(0, 0));
    cbh[1] = *(const half8*)(WTH + bofs(0, 1));

    if (XIN) {
#pragma unroll
        for (int q = 0; q < 8; q++) {
            int lin = t + q * 256;
            int r = lin >> 5, c4 = lin & 31;
            float4 v = make_float4(0.f, 0.f, 0.f, 0.f);
            if (row0 + r < M) v = ((const float4*)(X + (size_t)(row0 + r) * NF))[c4];
            half4v hv = {(f16)v.x, (f16)v.y, (f16)v.z, (f16)v.w};
            *(half4v*)&As[r * 136 + c4 * 4] = hv;
        }
    } else {
#pragma unroll
        for (int q = 0; q < 4; q++) {
            int lin = t + q * 256;
            int r = lin >> 4, c8 = lin & 15;
            half8 v = {};
            if (row0 + r < M) v = *(const half8*)(A + (size_t)(row0 + r) * NF + c8 * 8);
            *(half8*)&As[r * 136 + c8 * 8] = v;
        }
    }
    __syncthreads();

    float4v acc[2][4];
#pragma unroll
    for (int ct = 0; ct < 2; ct++)
#pragma unroll
        for (int rt = 0; rt < 4; rt++) acc[ct][rt] = (float4v)0.f;

#pragma unroll
    for (int s = 0; s < 4; s++) {
        half8 nbh[2];
        if (s < 3) {   // prefetch next K-step's B while MFMA'ing this one
            nbh[0] = *(const half8*)(WTH + bofs(s + 1, 0));
            nbh[1] = *(const half8*)(WTH + bofs(s + 1, 1));
        }
        half8 fa[4];
#pragma unroll
        for (int rt = 0; rt < 4; rt++)
            fa[rt] = *(half8*)&As[(rt * 16 + nl) * 136 + s * 32 + quad * 8];
#pragma unroll
        for (int ct = 0; ct < 2; ct++)
#pragma unroll
            for (int rt = 0; rt < 4; rt++)
                acc[ct][rt] = __builtin_amdgcn_mfma_f32_16x16x32_f16(fa[rt], cbh[ct], acc[ct][rt], 0, 0, 0);
        if (s < 3) {
            cbh[0] = nbh[0]; cbh[1] = nbh[1];
        }
    }

    __syncthreads();
#pragma unroll
    for (int ct = 0; ct < 2; ct++)
#pragma unroll
        for (int rt = 0; rt < 4; rt++)
#pragma unroll
            for (int r = 0; r < 4; r++)
                As[(rt * 16 + quad * 4 + r) * 136 + wave * 32 + ct * 16 + nl] =
                    (f16)acc[ct][rt][r];
    __syncthreads();
#pragma unroll
    for (int q = 0; q < 4; q++) {
        int lin = t + q * 256;
        int r = lin >> 4, c8 = lin & 15;
        if (row0 + r < M)
            *(half8*)(Z + (size_t)(row0 + r) * NF + c8 * 8) = *(half8*)&As[r * 136 + c8 * 8];
    }
}

// ---------------- aggregation (R7/R11-proven, frozen) ----------------------

#define ACHUNK 4

__global__ __launch_bounds__(256) void k_agg(const f16* __restrict__ z,
                                             const float* __restrict__ dinv,
                                             const int* __restrict__ row_ptr,
                                             const int* __restrict__ col,
                                             const float* __restrict__ bias,
                                             f16* __restrict__ h) {
    const int t = threadIdx.x;
    const int slot = t >> 4;            // 0..15 in block
    const int fl = t & 15;              // half8 chunk within row
    const int sbase = (t & 48);         // slot base lane within wave
    const int n0 = (blockIdx.x * 16 + slot) * ACHUNK;
    const half8* z8 = (const half8*)z;

    float bb[8];
    {
        float4 b0 = ((const float4*)bias)[fl * 2];
        float4 b1 = ((const float4*)bias)[fl * 2 + 1];
        bb[0] = b0.x; bb[1] = b0.y; bb[2] = b0.z; bb[3] = b0.w;
        bb[4] = b1.x; bb[5] = b1.y; bb[6] = b1.z; bb[7] = b1.w;
    }

    for (int n = n0; n < n0 + ACHUNK && n < N_NODES; n++) {
        const float di = dinv[n];
        const int beg = row_ptr[n];
        const int end = row_ptr[n + 1];

        float acc[8];
        {   // self-loop + bias
            half8 v = z8[(size_t)n * 16 + fl];
            float w = di * di;
#pragma unroll
            for (int j = 0; j < 8; j++) acc[j] = bb[j] + (float)v[j] * w;
        }

        for (int c = beg; c < end; c += 16) {
            int mcnt = end - c; if (mcnt > 16) mcnt = 16;
            int ce = c + fl;
            int colv = (ce < end) ? col[ce] : 0;
            float dvv = dinv[colv];

            int j = 0;
            for (; j + 1 < mcnt; j += 2) {
                int s1 = __shfl(colv, sbase + j, 64);
                float w1 = __shfl(dvv, sbase + j, 64) * di;
                int s2 = __shfl(colv, sbase + j + 1, 64);
                float w2 = __shfl(dvv, sbase + j + 1, 64) * di;
                half8 v1 = z8[(size_t)s1 * 16 + fl];
                half8 v2 = z8[(size_t)s2 * 16 + fl];
#pragma unroll
                for (int q = 0; q < 8; q++) acc[q] += (float)v1[q] * w1;
#pragma unroll
                for (int q = 0; q < 8; q++) acc[q] += (float)v2[q] * w2;
            }
            if (j < mcnt) {
                int s1 = __shfl(colv, sbase + j, 64);
                float w1 = __shfl(dvv, sbase + j, 64) * di;
                half8 v1 = z8[(size_t)s1 * 16 + fl];
#pragma unroll
                for (int q = 0; q < 8; q++) acc[q] += (float)v1[q] * w1;
            }
        }

        half8 o;
#pragma unroll
        for (int j = 0; j < 8; j++) o[j] = (f16)fmaxf(acc[j], 0.f);
        ((half8*)h)[(size_t)n * 16 + fl] = o;
    }
}

// ---------------- node-parallel mean pool (R11-proven pool2, frozen) --------

#define POOL_CHUNK 64

__global__ __launch_bounds__(128) void k_pool2(const f16* __restrict__ h,
                                               const int* __restrict__ batch,
                                               float* __restrict__ pooled) {
    int f = threadIdx.x;
    int n0 = blockIdx.x * POOL_CHUNK;
    int n1 = n0 + POOL_CHUNK;
    if (n1 > N_NODES) n1 = N_NODES;
    if (n0 >= N_NODES) return;
    int g = batch[n0];
    float acc = 0.f;
    for (int n = n0; n < n1; n++) {
        int gn = batch[n];
        if (gn != g) {
            atomicAdd(&pooled[g * NF + f], acc);
            acc = 0.f;
            g = gn;
        }
        acc += (float)h[(size_t)n * NF + f];   // h already relu'd
    }
    atomicAdd(&pooled[g * NF + f], acc);
}

// ---------------- summary MLP ----------------

__global__ void k_mlp(const float* __restrict__ pooled, const int* __restrict__ batch,
                      const float* __restrict__ Ws1, const float* __restrict__ bs1,
                      const float* __restrict__ Ws2, const float* __restrict__ bs2,
                      float* __restrict__ out) {
    __shared__ float row[NF];
    __shared__ float red[NF];
    int g = blockIdx.x, f = threadIdx.x;
    int lo = 0, hi = N_NODES;
    while (lo < hi) { int mid = (lo + hi) >> 1; if (batch[mid] < g) lo = mid + 1; else hi = mid; }
    int start = lo;
    hi = N_NODES;
    while (lo < hi) { int mid = (lo + hi) >> 1; if (batch[mid] < g + 1) lo = mid + 1; else hi = mid; }
    float cnt = (float)(lo - start);
    row[f] = pooled[g * NF + f] / fmaxf(cnt, 1.f);
    __syncthreads();
    float t = bs1[f];
    for (int k = 0; k < NF; k++) t += row[k] * Ws1[k * NF + f];
    t = fmaxf(t, 0.f);
    red[f] = t * Ws2[f];
    __syncthreads();
    for (int s = 64; s > 0; s >>= 1) {
        if (f < s) red[f] += red[f + s];
        __syncthreads();
    }
    if (f == 0) out[g] = red[0] + bs2[0];
}

// ---------------- driver ----------------

extern "C" void kernel_launch(void* const* d_in, const int* in_sizes, int n_in,
                              void* d_out, int out_size, void* d_ws, size_t ws_size,
                              hipStream_t stream) {
    const float* x    = (const float*)d_in[0];
    const int*   ei   = (const int*)d_in[1];
    const int*   batch= (const int*)d_in[2];
    const float* W1 = (const float*)d_in[3];  const float* b1 = (const float*)d_in[4];
    const float* W2 = (const float*)d_in[5];  const float* b2 = (const float*)d_in[6];
    const float* W3 = (const float*)d_in[7];  const float* b3 = (const float*)d_in[8];
    const float* W4 = (const float*)d_in[9];  const float* b4 = (const float*)d_in[10];
    const float* Ws1= (const float*)d_in[11]; const float* bs1= (const float*)d_in[12];
    const float* Ws2= (const float*)d_in[13]; const float* bs2= (const float*)d_in[14];
    float* out = (float*)d_out;

    char* ws = (char*)d_ws;
    size_t off = 0;
    auto alloc = [&](size_t bytes) {
        void* p = ws + off;
        off += (bytes + 255) & ~(size_t)255;
        return p;
    };
    f16*   bufZ   = (f16*)alloc((size_t)N_NODES * NF * 2);
    f16*   bufH   = (f16*)alloc((size_t)N_NODES * NF * 2);
    f16*   wtH    = (f16*)alloc((size_t)4 * NF * NF * 2);
    int*   counts = (int*)alloc((size_t)N_NODES * 4);
    int*   row_ptr= (int*)alloc((size_t)(N_NODES + 1) * 4);
    int*   cursor = (int*)alloc((size_t)N_NODES * 4);
    int*   col    = (int*)alloc((size_t)N_EDGES * 4);
    int*   bsums  = (int*)alloc(64 * 4);
    float* dinv   = (float*)alloc((size_t)N_NODES * 4);
    float* pooled = (float*)alloc((size_t)NG * NF * 4);

    hipMemsetAsync(counts, 0, (size_t)N_NODES * 4, stream);
    hipMemsetAsync(pooled, 0, (size_t)NG * NF * 4, stream);
    k_count<<<(N_EDGES + 255) / 256, 256, 0, stream>>>(ei, counts);
    int nscan = (N_NODES + 2047) / 2048;  // 49
    k_scan1<<<nscan, 256, 0, stream>>>(counts, row_ptr, bsums, dinv);
    k_scan3<<<(N_NODES + 255) / 256, 256, 0, stream>>>(row_ptr, bsums, cursor);
    k_fill<<<(N_EDGES + 255) / 256, 256, 0, stream>>>(ei, cursor, col,
                                                      W1, W2, W3, W4, wtH);

    int gblocks = (N_NODES + 63) / 64;                          // 1563
    int ablocks = (N_NODES + 16 * ACHUNK - 1) / (16 * ACHUNK);  // 1563
    k_gemm_mfma<1><<<gblocks, 256, 0, stream>>>(x, nullptr, wtH, bufZ, N_NODES);
    k_agg<<<ablocks, 256, 0, stream>>>(bufZ, dinv, row_ptr, col, b1, bufH);
    k_gemm_mfma<0><<<gblocks, 256, 0, stream>>>(nullptr, bufH, wtH + 16384, bufZ, N_NODES);
    k_agg<<<ablocks, 256, 0, stream>>>(bufZ, dinv, row_ptr, col, b2, bufH);
    k_gemm_mfma<0><<<gblocks, 256, 0, stream>>>(nullptr, bufH, wtH + 32768, bufZ, N_NODES);
    k_agg<<<ablocks, 256, 0, stream>>>(bufZ, dinv, row_ptr, col, b3, bufH);
    k_gemm_mfma<0><<<gblocks, 256, 0, stream>>>(nullptr, bufH, wtH + 49152, bufZ, N_NODES);
    k_agg<<<ablocks, 256, 0, stream>>>(bufZ, dinv, row_ptr, col, b4, bufH);

    int pblocks = (N_NODES + POOL_CHUNK - 1) / POOL_CHUNK;      // 1563
    k_pool2<<<pblocks, 128, 0, stream>>>(bufH, batch, pooled);
    k_mlp<<<NG, 128, 0, stream>>>(pooled, batch, Ws1, bs1, Ws2, bs2, out);
}